// Round 15
// baseline (203.254 us; speedup 1.0000x reference)
//
#include <hip/hip_runtime.h>
#include <hip/hip_bf16.h>
#include <stdint.h>

#define DIM 2048
#define TSEQ 2048
#define BATCH 2
#define NH 32
#define NKV 4
#define HD 64
#define MROWS (BATCH*TSEQ)   // 4096
#define NQKV 2560            // 2048 q + 256 k + 256 v

typedef __attribute__((ext_vector_type(4))) float f32x4;
typedef __attribute__((ext_vector_type(8))) __bf16 bf16x8;
typedef unsigned short ushort_t;

// async global->LDS, 16B/lane: LDS dest = wave-uniform base + lane*16
#define GLDS16(g, l) __builtin_amdgcn_global_load_lds( \
    (const __attribute__((address_space(1))) void*)(g), \
    (__attribute__((address_space(3))) void*)(l), 16, 0, 0)

__device__ __forceinline__ float bflo2f(unsigned int w) {
  union { unsigned int i; float f; } c; c.i = w << 16; return c.f;
}
__device__ __forceinline__ unsigned short f2bf(float f) {
  union { float f; unsigned int i; } c; c.f = f;
  unsigned int x = c.i;
  x += 0x7fffu + ((x >> 16) & 1u);   // RTNE
  return (unsigned short)(x >> 16);
}
__device__ __forceinline__ unsigned short f2bf_fast(float f) {
  union { float f; unsigned int i; } c; c.f = f;
  return (unsigned short)((c.i + 0x8000u) >> 16);   // round-half-up
}

// ---------------- cast x (f32 -> bf16), 4 elems/thread ----------------
__global__ void cast_bf16_k(const float* __restrict__ in, ushort_t* __restrict__ out, int n4) {
  const int i = blockIdx.x * 256 + threadIdx.x;
  if (i >= n4) return;
  const float4 v = ((const float4*)in)[i];
  uint2 p;
  p.x = (unsigned int)f2bf(v.x) | ((unsigned int)f2bf(v.y) << 16);
  p.y = (unsigned int)f2bf(v.z) | ((unsigned int)f2bf(v.w) << 16);
  ((uint2*)out)[i] = p;
}

// ---------------- fused transpose-cast of all four weights ----------------
__global__ void transpose_cast_all(const float* __restrict__ wq, const float* __restrict__ wk,
                                   const float* __restrict__ wv, const float* __restrict__ wo,
                                   ushort_t* __restrict__ wtq, ushort_t* __restrict__ woT) {
  __shared__ float tile[32][33];
  const int by = blockIdx.y;
  const float* src; ushort_t* dst; int N, bnb;
  if (by < 64)      { src = wq; dst = wtq;                    N = DIM; bnb = by; }
  else if (by < 72) { src = wk; dst = wtq + (long)DIM  * DIM; N = 256; bnb = by - 64; }
  else if (by < 80) { src = wv; dst = wtq + (long)2304 * DIM; N = 256; bnb = by - 72; }
  else              { src = wo; dst = woT;                    N = DIM; bnb = by - 80; }
  const int bk = blockIdx.x * 32;
  const int bn = bnb * 32;
  const int tx = threadIdx.x & 31;
  const int ty = threadIdx.x >> 5;  // 0..7
#pragma unroll
  for (int p = 0; p < 4; p++) {
    const int r = ty + p * 8;
    tile[r][tx] = src[(long)(bk + r) * N + bn + tx];
  }
  __syncthreads();
#pragma unroll
  for (int p = 0; p < 4; p++) {
    const int r = ty + p * 8;
    dst[(long)(bn + r) * DIM + bk + tx] = f2bf(tile[tx][r]);
  }
}

// ---------------- RoPE cos/sin table: [t][d] -> (cos, sin), 2048x32 ----------------
#define LOG1E4_D32 0.2878231366242557f   // ln(10000)/32
#define QSCALE 0.1803368801111243f       // 0.125 * log2(e)

__global__ void rope_tab_k(float2* __restrict__ tab) {
  const int i = blockIdx.x * 256 + threadIdx.x;   // 65536 = 2048*32
  const int t = i >> 5, d = i & 31;
  const float ang = (float)t * __expf(-(float)d * LOG1E4_D32);
  float s_, c_;
  __sincosf(ang, &s_, &c_);
  tab[i] = make_float2(c_, s_);
}

// ---------------- bf16 MFMA GEMM: C[M][N] = A[M][K] * BT[N][K]^T ----------------
// launch_bounds (256,4): R10 profile showed Occupancy 21% / MfmaUtil 23% at
// (256,2) — barrier-drain latency-bound at 2 blocks/CU. VGPR 76 and LDS 32KB
// permit 4 blocks/CU (cap 128 VGPR, 128KB LDS) -> more implicit wave overlap.
template<int EPI>
__global__ __launch_bounds__(256, 4) void gemm_bt(
    const ushort_t* __restrict__ A, const ushort_t* __restrict__ BT,
    int M, int N, int K,
    float* __restrict__ Cf, ushort_t* __restrict__ Cq,
    ushort_t* __restrict__ Ck, ushort_t* __restrict__ Cv,
    const float2* __restrict__ tab)
{
  __shared__ __align__(16) ushort_t As[128][64];
  __shared__ __align__(16) ushort_t Bs[128][64];
  const int tid  = threadIdx.x;
  const int lane = tid & 63;
  const int wid  = tid >> 6;
  const int wm   = wid >> 1, wn = wid & 1;   // 2x2 wave grid, 64x64 out each
  const int l8   = lane >> 3;                // 0..7: row within an 8-row chunk
  const int c8   = (lane & 7) * 8;           // ushort col within a 128B row
  const long abase = (long)blockIdx.x * 128 * K;
  const long bbase = (long)blockIdx.y * 128 * K;
  const int rsel = lane & 15;
  const int koff = (lane >> 4) * 8;
  f32x4 acc[4][4] = {};

  for (int k0 = 0; k0 < K; k0 += 64) {
    __syncthreads();   // previous-iter LDS reads complete
#pragma unroll
    for (int i = 0; i < 4; i++) {
      const int r0 = wid * 32 + i * 8;       // 8-row chunk staged per call
      GLDS16(&A [abase + (long)(r0 + l8) * K + k0 + c8], &As[r0][0]);
      GLDS16(&BT[bbase + (long)(r0 + l8) * K + k0 + c8], &Bs[r0][0]);
    }
    __syncthreads();   // vmcnt(0) drains the global_load_lds queue
#pragma unroll
    for (int kk = 0; kk < 64; kk += 32) {
      bf16x8 af[4], bfr[4];
#pragma unroll
      for (int m = 0; m < 4; m++) af[m]  = *(const bf16x8*)(&As[wm*64 + m*16 + rsel][kk + koff]);
#pragma unroll
      for (int n = 0; n < 4; n++) bfr[n] = *(const bf16x8*)(&Bs[wn*64 + n*16 + rsel][kk + koff]);
#pragma unroll
      for (int m = 0; m < 4; m++)
#pragma unroll
        for (int n = 0; n < 4; n++)
          acc[m][n] = __builtin_amdgcn_mfma_f32_16x16x32_bf16(af[m], bfr[n], acc[m][n], 0, 0, 0);
    }
  }

  const int rbase = blockIdx.x * 128 + wm * 64 + (lane >> 4) * 4;
  const int l15e  = lane & 15;

  if (EPI == 1) {
    const int cbase = blockIdx.y * 128 + wn * 64 + l15e;
#pragma unroll
    for (int m = 0; m < 4; m++)
#pragma unroll
      for (int n = 0; n < 4; n++) {
        const int gn = cbase + n * 16;
#pragma unroll
        for (int j = 0; j < 4; j++)
          Cf[(long)(rbase + m * 16 + j) * N + gn] = acc[m][n][j];
      }
  } else {
    const int colbase = blockIdx.y * 128 + wn * 64;   // wave-uniform, head-aligned
    if (colbase >= DIM + 256) {
      // V region: transposed store [B,Hkv,D,T], j packed (4 consecutive t)
#pragma unroll
      for (int m = 0; m < 4; m++) {
        const int gm0 = rbase + m * 16;
        const int b = gm0 >> 11;
        const int t = gm0 & (TSEQ - 1);
#pragma unroll
        for (int n = 0; n < 4; n++) {
          const int x = colbase + n * 16 + l15e - DIM;
          const int hkv = (x >> 6) & 3;
          const int d = x & 63;
          uint2 pk;
          pk.x = (unsigned int)f2bf(acc[m][n][0]) | ((unsigned int)f2bf(acc[m][n][1]) << 16);
          pk.y = (unsigned int)f2bf(acc[m][n][2]) | ((unsigned int)f2bf(acc[m][n][3]) << 16);
          *(uint2*)(&Cv[((long)(b * NKV + hkv) * HD + d) * TSEQ + t]) = pk;
        }
      }
    } else {
      const bool isQ = (colbase < DIM);
      const int hkv = (colbase - DIM) >> 6;            // K region only
#pragma unroll
      for (int m = 0; m < 4; m++) {
#pragma unroll
        for (int j = 0; j < 4; j++) {
          const int gm = rbase + m * 16 + j;
          const int t = gm & (TSEQ - 1);
          const int b = gm >> 11;
          const float2 cs0 = tab[t * 32 + l15e];
          const float2 cs1 = tab[t * 32 + 16 + l15e];
          const float v0 = acc[m][0][j], v1 = acc[m][1][j];
          const float v2 = acc[m][2][j], v3 = acc[m][3][j];
          const float r0 = v0 * cs0.x - v2 * cs0.y;
          const float r2 = v2 * cs0.x + v0 * cs0.y;
          const float r1 = v1 * cs1.x - v3 * cs1.y;
          const float r3 = v3 * cs1.x + v1 * cs1.y;
          if (isQ) {
            const long base = (long)gm * DIM + colbase + l15e;
            Cq[base]      = f2bf(r0 * QSCALE);
            Cq[base + 16] = f2bf(r1 * QSCALE);
            Cq[base + 32] = f2bf(r2 * QSCALE);
            Cq[base + 48] = f2bf(r3 * QSCALE);
          } else {
            const long base = ((long)(b * NKV + hkv) * TSEQ + t) * HD + l15e;
            Ck[base]      = f2bf(r0);
            Ck[base + 16] = f2bf(r1);
            Ck[base + 32] = f2bf(r2);
            Ck[base + 48] = f2bf(r3);
          }
        }
      }
    }
  }
}

// ---------------- MFMA flash attention: triangle-fold, 4-wave blocks ----------------
// (R13-exact, known-good: 74.2us. R14's shared-fragment interleave miscompiled
// — absmax 16 with no identifiable source-level bug; reverted per methodology.)
// 4 waves, QBLK=64/tile, paired tiles qtA=31-pq / qtB=pq; 1024 blocks,
// uniform 33 units, 4 blocks/CU. dbuf swizzled K/V LDS, one raw
// lgkmcnt(0)+s_barrier per iter; T5 setprio; swapped QK^T; NO-MAX exp2
// softmax; deferred l; in-register P redistribution.
__global__ __launch_bounds__(256, 4) void attn_mfma(
    const ushort_t* __restrict__ q, const ushort_t* __restrict__ k,
    const ushort_t* __restrict__ vt, ushort_t* __restrict__ o)
{
  __shared__ __align__(16) ushort_t Ks[2][64][64];    // [buf][key][d]   swz
  __shared__ __align__(16) ushort_t Vs[2][64][64];    // [buf][d][key]   swz

  const int tid  = threadIdx.x;
  const int lane = tid & 63;
  const int wid  = tid >> 6;          // 0..3
  const int l15  = lane & 15;
  const int lg   = lane >> 4;         // 0..3
  const int od   = lg & 1;
  const int hi   = lg >> 1;
  const int sw   = l15 & 7;           // read-side swizzle key (row&7 = l15&7)

  const int bh  = blockIdx.x & 63;
  const int pq  = blockIdx.x >> 6;    // 0..15
  const int qtA = 31 - pq;            // big tile (QBLK=64)
  const int qtB = pq;                 // small tile
  const int h   = bh & (NH - 1);
  const int b   = bh >> 5;
  const int hkv = h >> 3;
  const int qA0 = qtA * 64 + wid * 16;
  const int qB0 = qtB * 64 + wid * 16;

  // Q fragments for both tiles (MFMA B-operand layout).
  bf16x8 qfA0, qfA1, qfB0, qfB1;
  {
    const ushort_t* qp = q + ((long)(b * TSEQ) + qA0 + l15) * DIM + h * 64 + lg * 8;
    qfA0 = *(const bf16x8*)(qp);
    qfA1 = *(const bf16x8*)(qp + 32);
    const ushort_t* qp2 = q + ((long)(b * TSEQ) + qB0 + l15) * DIM + h * 64 + lg * 8;
    qfB0 = *(const bf16x8*)(qp2);
    qfB1 = *(const bf16x8*)(qp2 + 32);
  }

  const ushort_t* kb_ = k  + (long)(b * NKV + hkv) * TSEQ * HD;
  const ushort_t* vb_ = vt + (long)(b * NKV + hkv) * HD * TSEQ;

  float lA = 0.f, lB = 0.f;           // per-lane PARTIAL denoms
  f32x4 oA[4] = {}, oB[4] = {};       // row q = lg*4+j, col d = nt*16+l15

  // staging (256 threads): row tid>>2, two 8-ushort granules per array
  const int srow = tid >> 2;          // 0..63
  const int sgc  = (tid & 3) * 16;    // ushort col in global (two uint4)
  const int g0   = 2 * (tid & 3);     // granule indices
  const int slc0 = ((g0    ) ^ (srow & 7)) * 8;
  const int slc1 = ((g0 + 1) ^ (srow & 7)) * 8;

  // V-read swizzled granule cols for the permuted PV k-slots
  const int gv0 = ((0 + 2 * od + hi) ^ sw) * 8;
  const int gv1 = ((4 + 2 * od + hi) ^ sw) * 8;

  const int nkv = qtA + 1;

  // prologue: stage KV tile 0 into buf 0 (swizzled)
  *(uint4*)(&Ks[0][srow][slc0]) = *(const uint4*)(&kb_[(long)srow * HD + sgc]);
  *(uint4*)(&Ks[0][srow][slc1]) = *(const uint4*)(&kb_[(long)srow * HD + sgc + 8]);
  *(uint4*)(&Vs[0][srow][slc0]) = *(const uint4*)(&vb_[(long)srow * TSEQ + sgc]);
  *(uint4*)(&Vs[0][srow][slc1]) = *(const uint4*)(&vb_[(long)srow * TSEQ + sgc + 8]);
  int cur = 0;

#define PACK_KT(KT, UA, UB, LL) { \
    const float p0 = exp2f(st[KT][0]); \
    const float p1 = exp2f(st[KT][1]); \
    const float p2 = exp2f(st[KT][2]); \
    const float p3 = exp2f(st[KT][3]); \
    LL += (p0 + p1) + (p2 + p3); \
    asm("v_cvt_pk_bf16_f32 %0, %1, %2" : "=v"(UA) : "v"(p0), "v"(p1)); \
    asm("v_cvt_pk_bf16_f32 %0, %1, %2" : "=v"(UB) : "v"(p2), "v"(p3)); \
  }

#define PROC_TILE(QF0, QF1, OO, LL, Q0) \
  if (kb0 <= (Q0) + 15) { \
    f32x4 st[4] = {}; \
    __builtin_amdgcn_s_setprio(1); \
    _Pragma("unroll") \
    for (int kt = 0; kt < 4; kt++) { \
      const bf16x8 kf0 = *(const bf16x8*)(&Ks[cur][kt * 16 + l15][((0 + lg) ^ sw) * 8]); \
      st[kt] = __builtin_amdgcn_mfma_f32_16x16x32_bf16(kf0, QF0, st[kt], 0, 0, 0); \
      const bf16x8 kf1 = *(const bf16x8*)(&Ks[cur][kt * 16 + l15][((4 + lg) ^ sw) * 8]); \
      st[kt] = __builtin_amdgcn_mfma_f32_16x16x32_bf16(kf1, QF1, st[kt], 0, 0, 0); \
    } \
    __builtin_amdgcn_s_setprio(0); \
    if (kb0 + 63 > (Q0)) { \
      const int qg = (Q0) + l15; \
      _Pragma("unroll") \
      for (int kt = 0; kt < 4; kt++) { \
        const int kg0 = kb0 + kt * 16 + lg * 4; \
        _Pragma("unroll") \
        for (int j = 0; j < 4; j++) { \
          if (kg0 + j > qg) st[kt][j] = -1e30f; \
        } \
      } \
    } \
    unsigned int u00, u01, u10, u11, u20, u21, u30, u31; \
    PACK_KT(0, u00, u01, LL) \
    PACK_KT(1, u10, u11, LL) \
    PACK_KT(2, u20, u21, LL) \
    PACK_KT(3, u30, u31, LL) \
    const unsigned int r00 = __shfl_xor((int)(od ? u00 : u10), 16, 64); \
    const unsigned int r01 = __shfl_xor((int)(od ? u01 : u11), 16, 64); \
    const unsigned int r10 = __shfl_xor((int)(od ? u20 : u30), 16, 64); \
    const unsigned int r11 = __shfl_xor((int)(od ? u21 : u31), 16, 64); \
    union { unsigned int u[4]; bf16x8 v; } T0, T1; \
    T0.u[0] = od ? r00 : u00;  T0.u[1] = od ? r01 : u01; \
    T0.u[2] = od ? u10 : r00;  T0.u[3] = od ? u11 : r01; \
    T1.u[0] = od ? r10 : u20;  T1.u[1] = od ? r11 : u21; \
    T1.u[2] = od ? u30 : r10;  T1.u[3] = od ? u31 : r11; \
    __builtin_amdgcn_s_setprio(1); \
    _Pragma("unroll") \
    for (int nt = 0; nt < 4; nt++) { \
      const bf16x8 vf0 = *(const bf16x8*)(&Vs[cur][nt * 16 + l15][gv0]); \
      OO[nt] = __builtin_amdgcn_mfma_f32_16x16x32_bf16(T0.v, vf0, OO[nt], 0, 0, 0); \
    } \
    _Pragma("unroll") \
    for (int nt = 0; nt < 4; nt++) { \
      const bf16x8 vf1 = *(const bf16x8*)(&Vs[cur][nt * 16 + l15][gv1]); \
      OO[nt] = __builtin_amdgcn_mfma_f32_16x16x32_bf16(T1.v, vf1, OO[nt], 0, 0, 0); \
    } \
    __builtin_amdgcn_s_setprio(0); \
  }

  for (int kbv = 0; kbv < nkv; kbv++) {
    const int kb0 = kbv * 64;
    const bool pf = (kbv + 1 < nkv);
    uint4 kr0 = {}, kr1 = {}, vr0 = {}, vr1 = {};
    if (pf) {   // issue next-tile loads early; vmcnt waited at the ds_write below
      kr0 = *(const uint4*)(&kb_[(long)(kb0 + 64 + srow) * HD + sgc]);
      kr1 = *(const uint4*)(&kb_[(long)(kb0 + 64 + srow) * HD + sgc + 8]);
      vr0 = *(const uint4*)(&vb_[(long)srow * TSEQ + kb0 + 64 + sgc]);
      vr1 = *(const uint4*)(&vb_[(long)srow * TSEQ + kb0 + 64 + sgc + 8]);
    }
    // drain own LDS ops, then sync (no vmcnt drain -> prefetch stays in flight)
    asm volatile("s_waitcnt lgkmcnt(0)\n\ts_barrier" ::: "memory");

    PROC_TILE(qfA0, qfA1, oA, lA, qA0)
    PROC_TILE(qfB0, qfB1, oB, lB, qB0)

    if (pf) {   // write prefetched tile into the other buffer (vmcnt wait here)
      *(uint4*)(&Ks[cur ^ 1][srow][slc0]) = kr0;
      *(uint4*)(&Ks[cur ^ 1][srow][slc1]) = kr1;
      *(uint4*)(&Vs[cur ^ 1][srow][slc0]) = vr0;
      *(uint4*)(&Vs[cur ^ 1][srow][slc1]) = vr1;
    }
    cur ^= 1;
  }
#undef PROC_TILE
#undef PACK_KT

  // epilogue: finish deferred l reductions, normalize, store bf16 (both tiles)
  {
    float lc = lA;
    lc += __shfl_xor(lc, 16, 64);
    lc += __shfl_xor(lc, 32, 64);
    const long orow = (long)(b * TSEQ) + qA0;
#pragma unroll
    for (int j = 0; j < 4; j++) {
      const float inv = 1.f / __shfl(lc, (lane & 48) | (lg * 4 + j), 64);
#pragma unroll
      for (int nt = 0; nt < 4; nt++)
        o[(orow + lg * 4 + j) * DIM + h * 64 + nt * 16 + l15] = f2bf_fast(oA[nt][j] * inv);
    }
  }
  {
    float lc = lB;
    lc += __shfl_xor(lc, 16, 64);
    lc += __shfl_xor(lc, 32, 64);
    const long orow = (long)(b * TSEQ) + qB0;
#pragma unroll
    for (int j = 0; j < 4; j++) {
      const float inv = 1.f / __shfl(lc, (lane & 48) | (lg * 4 + j), 64);
#pragma unroll
      for (int nt = 0; nt < 4; nt++)
        o[(orow + lg * 4 + j) * DIM + h * 64 + nt * 16 + l15] = f2bf_fast(oB[nt][j] * inv);
    }
  }
}

// ---------------- launch ----------------
extern "C" void kernel_launch(void* const* d_in, const int* in_sizes, int n_in,
                              void* d_out, int out_size, void* d_ws, size_t ws_size,
                              hipStream_t stream) {
  const float* x  = (const float*)d_in[0];
  const float* wq = (const float*)d_in[1];
  const float* wk = (const float*)d_in[2];
  const float* wv = (const float*)d_in[3];
  const float* wo = (const float*)d_in[4];
  float* out = (float*)d_out;

  ushort_t* ws = (ushort_t*)d_ws;
  const long NXB = (long)MROWS * DIM;               // 8388608
  ushort_t* xb   = ws;
  ushort_t* wtq  = xb  + NXB;                       // [2560][2048]
  ushort_t* woT  = wtq + (long)NQKV * DIM;          // [2048][2048]
  ushort_t* qws  = woT + (long)DIM * DIM;           // [4096][2048]
  ushort_t* kws  = qws + NXB;                       // [B,Hkv,T,D]
  ushort_t* vtws = kws + (long)BATCH * NKV * TSEQ * HD;  // [B,Hkv,D,T]
  ushort_t* aws  = vtws + (long)BATCH * NKV * TSEQ * HD; // [4096][2048]
  float2*   tab  = (float2*)(aws + NXB);            // [2048][32] cos/sin

  cast_bf16_k<<<(int)(NXB / 1024), 256, 0, stream>>>(x, xb, (int)(NXB / 4));
  transpose_cast_all<<<dim3(64, 144), 256, 0, stream>>>(wq, wk, wv, wo, wtq, woT);
  rope_tab_k<<<256, 256, 0, stream>>>(tab);

  gemm_bt<0><<<dim3(32, 20), 256, 0, stream>>>(xb, wtq, MROWS, NQKV, DIM,
                                               nullptr, qws, kws, vtws, tab);

  attn_mfma<<<BATCH * NH * 16, 256, 0, stream>>>(qws, kws, vtws, aws);

  gemm_bt<1><<<dim3(32, 16), 256, 0, stream>>>(aws, woT, MROWS, DIM, DIM,
                                               out, nullptr, nullptr, nullptr, nullptr);
}

// Round 16
// 201.986 us; speedup vs baseline: 1.0063x; 1.0063x over previous
//
#include <hip/hip_runtime.h>
#include <hip/hip_bf16.h>
#include <stdint.h>

#define DIM 2048
#define TSEQ 2048
#define BATCH 2
#define NH 32
#define NKV 4
#define HD 64
#define MROWS (BATCH*TSEQ)   // 4096
#define NQKV 2560            // 2048 q + 256 k + 256 v

typedef __attribute__((ext_vector_type(4))) float f32x4;
typedef __attribute__((ext_vector_type(8))) __bf16 bf16x8;
typedef unsigned short ushort_t;

// async global->LDS, 16B/lane: LDS dest = wave-uniform base + lane*16
#define GLDS16(g, l) __builtin_amdgcn_global_load_lds( \
    (const __attribute__((address_space(1))) void*)(g), \
    (__attribute__((address_space(3))) void*)(l), 16, 0, 0)

__device__ __forceinline__ float bflo2f(unsigned int w) {
  union { unsigned int i; float f; } c; c.i = w << 16; return c.f;
}
__device__ __forceinline__ unsigned short f2bf(float f) {
  union { float f; unsigned int i; } c; c.f = f;
  unsigned int x = c.i;
  x += 0x7fffu + ((x >> 16) & 1u);   // RTNE
  return (unsigned short)(x >> 16);
}
__device__ __forceinline__ unsigned short f2bf_fast(float f) {
  union { float f; unsigned int i; } c; c.f = f;
  return (unsigned short)((c.i + 0x8000u) >> 16);   // round-half-up
}

// ---------------- cast x (f32 -> bf16), 4 elems/thread ----------------
__global__ void cast_bf16_k(const float* __restrict__ in, ushort_t* __restrict__ out, int n4) {
  const int i = blockIdx.x * 256 + threadIdx.x;
  if (i >= n4) return;
  const float4 v = ((const float4*)in)[i];
  uint2 p;
  p.x = (unsigned int)f2bf(v.x) | ((unsigned int)f2bf(v.y) << 16);
  p.y = (unsigned int)f2bf(v.z) | ((unsigned int)f2bf(v.w) << 16);
  ((uint2*)out)[i] = p;
}

// ---------------- fused transpose-cast of all four weights ----------------
__global__ void transpose_cast_all(const float* __restrict__ wq, const float* __restrict__ wk,
                                   const float* __restrict__ wv, const float* __restrict__ wo,
                                   ushort_t* __restrict__ wtq, ushort_t* __restrict__ woT) {
  __shared__ float tile[32][33];
  const int by = blockIdx.y;
  const float* src; ushort_t* dst; int N, bnb;
  if (by < 64)      { src = wq; dst = wtq;                    N = DIM; bnb = by; }
  else if (by < 72) { src = wk; dst = wtq + (long)DIM  * DIM; N = 256; bnb = by - 64; }
  else if (by < 80) { src = wv; dst = wtq + (long)2304 * DIM; N = 256; bnb = by - 72; }
  else              { src = wo; dst = woT;                    N = DIM; bnb = by - 80; }
  const int bk = blockIdx.x * 32;
  const int bn = bnb * 32;
  const int tx = threadIdx.x & 31;
  const int ty = threadIdx.x >> 5;  // 0..7
#pragma unroll
  for (int p = 0; p < 4; p++) {
    const int r = ty + p * 8;
    tile[r][tx] = src[(long)(bk + r) * N + bn + tx];
  }
  __syncthreads();
#pragma unroll
  for (int p = 0; p < 4; p++) {
    const int r = ty + p * 8;
    dst[(long)(bn + r) * DIM + bk + tx] = f2bf(tile[tx][r]);
  }
}

// ---------------- RoPE cos/sin table: [t][d] -> (cos, sin), 2048x32 ----------------
#define LOG1E4_D32 0.2878231366242557f   // ln(10000)/32
#define QSCALE 0.1803368801111243f       // 0.125 * log2(e)

__global__ void rope_tab_k(float2* __restrict__ tab) {
  const int i = blockIdx.x * 256 + threadIdx.x;   // 65536 = 2048*32
  const int t = i >> 5, d = i & 31;
  const float ang = (float)t * __expf(-(float)d * LOG1E4_D32);
  float s_, c_;
  __sincosf(ang, &s_, &c_);
  tab[i] = make_float2(c_, s_);
}

// ---------------- bf16 MFMA GEMM: C[M][N] = A[M][K] * BT[N][K]^T ----------------
template<int EPI>
__global__ __launch_bounds__(256, 4) void gemm_bt(
    const ushort_t* __restrict__ A, const ushort_t* __restrict__ BT,
    int M, int N, int K,
    float* __restrict__ Cf, ushort_t* __restrict__ Cq,
    ushort_t* __restrict__ Ck, ushort_t* __restrict__ Cv,
    const float2* __restrict__ tab)
{
  __shared__ __align__(16) ushort_t As[128][64];
  __shared__ __align__(16) ushort_t Bs[128][64];
  const int tid  = threadIdx.x;
  const int lane = tid & 63;
  const int wid  = tid >> 6;
  const int wm   = wid >> 1, wn = wid & 1;   // 2x2 wave grid, 64x64 out each
  const int l8   = lane >> 3;                // 0..7: row within an 8-row chunk
  const int c8   = (lane & 7) * 8;           // ushort col within a 128B row
  const long abase = (long)blockIdx.x * 128 * K;
  const long bbase = (long)blockIdx.y * 128 * K;
  const int rsel = lane & 15;
  const int koff = (lane >> 4) * 8;
  f32x4 acc[4][4] = {};

  for (int k0 = 0; k0 < K; k0 += 64) {
    __syncthreads();   // previous-iter LDS reads complete
#pragma unroll
    for (int i = 0; i < 4; i++) {
      const int r0 = wid * 32 + i * 8;       // 8-row chunk staged per call
      GLDS16(&A [abase + (long)(r0 + l8) * K + k0 + c8], &As[r0][0]);
      GLDS16(&BT[bbase + (long)(r0 + l8) * K + k0 + c8], &Bs[r0][0]);
    }
    __syncthreads();   // vmcnt(0) drains the global_load_lds queue
#pragma unroll
    for (int kk = 0; kk < 64; kk += 32) {
      bf16x8 af[4], bfr[4];
#pragma unroll
      for (int m = 0; m < 4; m++) af[m]  = *(const bf16x8*)(&As[wm*64 + m*16 + rsel][kk + koff]);
#pragma unroll
      for (int n = 0; n < 4; n++) bfr[n] = *(const bf16x8*)(&Bs[wn*64 + n*16 + rsel][kk + koff]);
#pragma unroll
      for (int m = 0; m < 4; m++)
#pragma unroll
        for (int n = 0; n < 4; n++)
          acc[m][n] = __builtin_amdgcn_mfma_f32_16x16x32_bf16(af[m], bfr[n], acc[m][n], 0, 0, 0);
    }
  }

  const int rbase = blockIdx.x * 128 + wm * 64 + (lane >> 4) * 4;
  const int l15e  = lane & 15;

  if (EPI == 1) {
    const int cbase = blockIdx.y * 128 + wn * 64 + l15e;
#pragma unroll
    for (int m = 0; m < 4; m++)
#pragma unroll
      for (int n = 0; n < 4; n++) {
        const int gn = cbase + n * 16;
#pragma unroll
        for (int j = 0; j < 4; j++)
          Cf[(long)(rbase + m * 16 + j) * N + gn] = acc[m][n][j];
      }
  } else {
    const int colbase = blockIdx.y * 128 + wn * 64;   // wave-uniform, head-aligned
    if (colbase >= DIM + 256) {
      // V region: transposed store [B,Hkv,D,T], j packed (4 consecutive t)
#pragma unroll
      for (int m = 0; m < 4; m++) {
        const int gm0 = rbase + m * 16;
        const int b = gm0 >> 11;
        const int t = gm0 & (TSEQ - 1);
#pragma unroll
        for (int n = 0; n < 4; n++) {
          const int x = colbase + n * 16 + l15e - DIM;
          const int hkv = (x >> 6) & 3;
          const int d = x & 63;
          uint2 pk;
          pk.x = (unsigned int)f2bf(acc[m][n][0]) | ((unsigned int)f2bf(acc[m][n][1]) << 16);
          pk.y = (unsigned int)f2bf(acc[m][n][2]) | ((unsigned int)f2bf(acc[m][n][3]) << 16);
          *(uint2*)(&Cv[((long)(b * NKV + hkv) * HD + d) * TSEQ + t]) = pk;
        }
      }
    } else {
      const bool isQ = (colbase < DIM);
      const int hkv = (colbase - DIM) >> 6;            // K region only
#pragma unroll
      for (int m = 0; m < 4; m++) {
#pragma unroll
        for (int j = 0; j < 4; j++) {
          const int gm = rbase + m * 16 + j;
          const int t = gm & (TSEQ - 1);
          const int b = gm >> 11;
          const float2 cs0 = tab[t * 32 + l15e];
          const float2 cs1 = tab[t * 32 + 16 + l15e];
          const float v0 = acc[m][0][j], v1 = acc[m][1][j];
          const float v2 = acc[m][2][j], v3 = acc[m][3][j];
          const float r0 = v0 * cs0.x - v2 * cs0.y;
          const float r2 = v2 * cs0.x + v0 * cs0.y;
          const float r1 = v1 * cs1.x - v3 * cs1.y;
          const float r3 = v3 * cs1.x + v1 * cs1.y;
          if (isQ) {
            const long base = (long)gm * DIM + colbase + l15e;
            Cq[base]      = f2bf(r0 * QSCALE);
            Cq[base + 16] = f2bf(r1 * QSCALE);
            Cq[base + 32] = f2bf(r2 * QSCALE);
            Cq[base + 48] = f2bf(r3 * QSCALE);
          } else {
            const long base = ((long)(b * NKV + hkv) * TSEQ + t) * HD + l15e;
            Ck[base]      = f2bf(r0);
            Ck[base + 16] = f2bf(r1);
            Ck[base + 32] = f2bf(r2);
            Ck[base + 48] = f2bf(r3);
          }
        }
      }
    }
  }
}

// ---------------- MFMA flash attention: 2 q-halves share K/V fragments ----------------
// R15 diagnosis: attn is LDS-BW-bound (2.2GB of ds_read_b128 ~= 41us floor).
// Fix: R10's proven geometry (4 waves, QBLK=128/block, 1024 blocks descending)
// but each wave owns 32 q rows as TWO 16-row halves, and the 8 K-frags +
// 8 V-frags are read ONCE into locals and reused by both halves -> LDS
// traffic halved (1.1GB). Control shape = R10/R13-proven: sequential MFMA
// clusters, wave-uniform guards OUTSIDE unrolled loops (R14's interleaved
// per-kt branching miscompiled; avoided).
// dbuf swizzled K/V LDS (32KB), one raw lgkmcnt(0)+s_barrier per iter;
// T5 setprio; swapped QK^T; NO-MAX exp2 softmax; deferred l reduction;
// in-register P redistribution (permuted PV k-slots).
// launch_bounds (256,3): VGPR cap ~170, peak ~150 live — must NOT spill (R8).
__global__ __launch_bounds__(256, 3) void attn_mfma(
    const ushort_t* __restrict__ q, const ushort_t* __restrict__ k,
    const ushort_t* __restrict__ vt, ushort_t* __restrict__ o)
{
  __shared__ __align__(16) ushort_t Ks[2][64][64];    // [buf][key][d]   swz
  __shared__ __align__(16) ushort_t Vs[2][64][64];    // [buf][d][key]   swz

  const int tid  = threadIdx.x;
  const int lane = tid & 63;
  const int wid  = tid >> 6;          // 0..3
  const int l15  = lane & 15;
  const int lg   = lane >> 4;         // 0..3
  const int od   = lg & 1;
  const int hi   = lg >> 1;
  const int sw   = l15 & 7;           // read-side swizzle key (row&7 = l15&7)

  const int bh  = blockIdx.x & 63;
  const int qt  = (TSEQ / 128 - 1) - (blockIdx.x >> 6);   // descending work
  const int h   = bh & (NH - 1);
  const int b   = bh >> 5;
  const int hkv = h >> 3;
  const int qw0 = qt * 128 + wid * 32;   // wave's first q row (owns 32)

  // Q fragments for both halves (MFMA B-operand layout).
  bf16x8 qf0c0, qf0c1, qf1c0, qf1c1;
  {
    const ushort_t* qp0 = q + ((long)(b * TSEQ) + qw0 + l15) * DIM + h * 64 + lg * 8;
    qf0c0 = *(const bf16x8*)(qp0);
    qf0c1 = *(const bf16x8*)(qp0 + 32);
    const ushort_t* qp1 = qp0 + 16 * DIM;
    qf1c0 = *(const bf16x8*)(qp1);
    qf1c1 = *(const bf16x8*)(qp1 + 32);
  }

  const ushort_t* kb_ = k  + (long)(b * NKV + hkv) * TSEQ * HD;
  const ushort_t* vb_ = vt + (long)(b * NKV + hkv) * HD * TSEQ;

  float lH0 = 0.f, lH1 = 0.f;         // per-lane PARTIAL denoms
  f32x4 oH0[4] = {}, oH1[4] = {};     // per half: row q = lg*4+j, col d = nt*16+l15

  // staging (256 threads): row tid>>2, two 8-ushort granules per array
  const int srow = tid >> 2;          // 0..63
  const int sgc  = (tid & 3) * 16;    // ushort col in global (two uint4)
  const int g0   = 2 * (tid & 3);     // granule indices
  const int slc0 = ((g0    ) ^ (srow & 7)) * 8;
  const int slc1 = ((g0 + 1) ^ (srow & 7)) * 8;

  // V-read swizzled granule cols for the permuted PV k-slots
  const int gv0 = ((0 + 2 * od + hi) ^ sw) * 8;
  const int gv1 = ((4 + 2 * od + hi) ^ sw) * 8;

  const int nkv = 2 * qt + 2;

  // prologue: stage KV tile 0 into buf 0 (swizzled)
  *(uint4*)(&Ks[0][srow][slc0]) = *(const uint4*)(&kb_[(long)srow * HD + sgc]);
  *(uint4*)(&Ks[0][srow][slc1]) = *(const uint4*)(&kb_[(long)srow * HD + sgc + 8]);
  *(uint4*)(&Vs[0][srow][slc0]) = *(const uint4*)(&vb_[(long)srow * TSEQ + sgc]);
  *(uint4*)(&Vs[0][srow][slc1]) = *(const uint4*)(&vb_[(long)srow * TSEQ + sgc + 8]);
  int cur = 0;

  union packu { unsigned int u[4]; bf16x8 v; };

#define PK(ST, KT, UA, UB, LL) { \
    const float p0 = exp2f(ST[KT][0]); \
    const float p1 = exp2f(ST[KT][1]); \
    const float p2 = exp2f(ST[KT][2]); \
    const float p3 = exp2f(ST[KT][3]); \
    LL += (p0 + p1) + (p2 + p3); \
    asm("v_cvt_pk_bf16_f32 %0, %1, %2" : "=v"(UA) : "v"(p0), "v"(p1)); \
    asm("v_cvt_pk_bf16_f32 %0, %1, %2" : "=v"(UB) : "v"(p2), "v"(p3)); \
  }

#define PACK_HALF(ST, LL, TT0, TT1) { \
    unsigned int u00, u01, u10, u11, u20, u21, u30, u31; \
    PK(ST, 0, u00, u01, LL) \
    PK(ST, 1, u10, u11, LL) \
    PK(ST, 2, u20, u21, LL) \
    PK(ST, 3, u30, u31, LL) \
    const unsigned int r00 = __shfl_xor((int)(od ? u00 : u10), 16, 64); \
    const unsigned int r01 = __shfl_xor((int)(od ? u01 : u11), 16, 64); \
    const unsigned int r10 = __shfl_xor((int)(od ? u20 : u30), 16, 64); \
    const unsigned int r11 = __shfl_xor((int)(od ? u21 : u31), 16, 64); \
    TT0.u[0] = od ? r00 : u00;  TT0.u[1] = od ? r01 : u01; \
    TT0.u[2] = od ? u10 : r00;  TT0.u[3] = od ? u11 : r01; \
    TT1.u[0] = od ? r10 : u20;  TT1.u[1] = od ? r11 : u21; \
    TT1.u[2] = od ? u30 : r10;  TT1.u[3] = od ? u31 : r11; \
  }

#define MASK_ST(ST, Q0) { \
    const int qg = (Q0) + l15; \
    _Pragma("unroll") \
    for (int kt = 0; kt < 4; kt++) { \
      const int kg0 = kb0 + kt * 16 + lg * 4; \
      _Pragma("unroll") \
      for (int j = 0; j < 4; j++) { \
        if (kg0 + j > qg) ST[kt][j] = -1e30f; \
      } \
    } \
  }

  for (int kbv = 0; kbv < nkv; kbv++) {
    const int kb0 = kbv * 64;
    const bool pf = (kbv + 1 < nkv);
    uint4 kr0 = {}, kr1 = {}, vr0 = {}, vr1 = {};
    if (pf) {   // issue next-tile loads early; vmcnt waited at the ds_write below
      kr0 = *(const uint4*)(&kb_[(long)(kb0 + 64 + srow) * HD + sgc]);
      kr1 = *(const uint4*)(&kb_[(long)(kb0 + 64 + srow) * HD + sgc + 8]);
      vr0 = *(const uint4*)(&vb_[(long)srow * TSEQ + kb0 + 64 + sgc]);
      vr1 = *(const uint4*)(&vb_[(long)srow * TSEQ + kb0 + 64 + sgc + 8]);
    }
    // drain own LDS ops, then sync (no vmcnt drain -> prefetch stays in flight)
    asm volatile("s_waitcnt lgkmcnt(0)\n\ts_barrier" ::: "memory");

    const bool a1 = (kb0 <= qw0 + 31);   // H1 active (implies wave active)
    if (a1) {
      const bool a0 = (kb0 <= qw0 + 15); // H0 active

      // K fragments read ONCE, shared by both halves
      bf16x8 kfa[4], kfb[4];
#pragma unroll
      for (int kt = 0; kt < 4; kt++) {
        kfa[kt] = *(const bf16x8*)(&Ks[cur][kt * 16 + l15][((0 + lg) ^ sw) * 8]);
        kfb[kt] = *(const bf16x8*)(&Ks[cur][kt * 16 + l15][((4 + lg) ^ sw) * 8]);
      }

      // QK^T per half (sequential clusters, guards outside loops)
      f32x4 st1[4] = {};
      __builtin_amdgcn_s_setprio(1);
#pragma unroll
      for (int kt = 0; kt < 4; kt++) {
        st1[kt] = __builtin_amdgcn_mfma_f32_16x16x32_bf16(kfa[kt], qf1c0, st1[kt], 0, 0, 0);
        st1[kt] = __builtin_amdgcn_mfma_f32_16x16x32_bf16(kfb[kt], qf1c1, st1[kt], 0, 0, 0);
      }
      __builtin_amdgcn_s_setprio(0);
      f32x4 st0[4] = {};
      if (a0) {
        __builtin_amdgcn_s_setprio(1);
#pragma unroll
        for (int kt = 0; kt < 4; kt++) {
          st0[kt] = __builtin_amdgcn_mfma_f32_16x16x32_bf16(kfa[kt], qf0c0, st0[kt], 0, 0, 0);
          st0[kt] = __builtin_amdgcn_mfma_f32_16x16x32_bf16(kfb[kt], qf0c1, st0[kt], 0, 0, 0);
        }
        __builtin_amdgcn_s_setprio(0);
      }

      // causal masks (diagonal region only)
      if (kb0 + 63 > qw0 + 16) MASK_ST(st1, qw0 + 16)
      if (a0 && kb0 + 63 > qw0) MASK_ST(st0, qw0)

      // softmax + pack + in-register redistribution per half
      packu T0H1, T1H1, T0H0, T1H0;
      PACK_HALF(st1, lH1, T0H1, T1H1)
      if (a0) PACK_HALF(st0, lH0, T0H0, T1H0)

      // V fragments read ONCE, shared by both halves
      bf16x8 vfa[4], vfb[4];
#pragma unroll
      for (int nt = 0; nt < 4; nt++) {
        vfa[nt] = *(const bf16x8*)(&Vs[cur][nt * 16 + l15][gv0]);
        vfb[nt] = *(const bf16x8*)(&Vs[cur][nt * 16 + l15][gv1]);
      }

      // PV per half
      __builtin_amdgcn_s_setprio(1);
#pragma unroll
      for (int nt = 0; nt < 4; nt++)
        oH1[nt] = __builtin_amdgcn_mfma_f32_16x16x32_bf16(T0H1.v, vfa[nt], oH1[nt], 0, 0, 0);
#pragma unroll
      for (int nt = 0; nt < 4; nt++)
        oH1[nt] = __builtin_amdgcn_mfma_f32_16x16x32_bf16(T1H1.v, vfb[nt], oH1[nt], 0, 0, 0);
      __builtin_amdgcn_s_setprio(0);
      if (a0) {
        __builtin_amdgcn_s_setprio(1);
#pragma unroll
        for (int nt = 0; nt < 4; nt++)
          oH0[nt] = __builtin_amdgcn_mfma_f32_16x16x32_bf16(T0H0.v, vfa[nt], oH0[nt], 0, 0, 0);
#pragma unroll
        for (int nt = 0; nt < 4; nt++)
          oH0[nt] = __builtin_amdgcn_mfma_f32_16x16x32_bf16(T1H0.v, vfb[nt], oH0[nt], 0, 0, 0);
        __builtin_amdgcn_s_setprio(0);
      }
    }

    if (pf) {   // write prefetched tile into the other buffer (vmcnt wait here)
      *(uint4*)(&Ks[cur ^ 1][srow][slc0]) = kr0;
      *(uint4*)(&Ks[cur ^ 1][srow][slc1]) = kr1;
      *(uint4*)(&Vs[cur ^ 1][srow][slc0]) = vr0;
      *(uint4*)(&Vs[cur ^ 1][srow][slc1]) = vr1;
    }
    cur ^= 1;
  }
#undef MASK_ST
#undef PACK_HALF
#undef PK

  // epilogue: finish deferred l reductions, normalize, store bf16 (both halves)
  {
    float lc = lH0;
    lc += __shfl_xor(lc, 16, 64);
    lc += __shfl_xor(lc, 32, 64);
    const long orow = (long)(b * TSEQ) + qw0;
#pragma unroll
    for (int j = 0; j < 4; j++) {
      const float inv = 1.f / __shfl(lc, (lane & 48) | (lg * 4 + j), 64);
#pragma unroll
      for (int nt = 0; nt < 4; nt++)
        o[(orow + lg * 4 + j) * DIM + h * 64 + nt * 16 + l15] = f2bf_fast(oH0[nt][j] * inv);
    }
  }
  {
    float lc = lH1;
    lc += __shfl_xor(lc, 16, 64);
    lc += __shfl_xor(lc, 32, 64);
    const long orow = (long)(b * TSEQ) + qw0 + 16;
#pragma unroll
    for (int j = 0; j < 4; j++) {
      const float inv = 1.f / __shfl(lc, (lane & 48) | (lg * 4 + j), 64);
#pragma unroll
      for (int nt = 0; nt < 4; nt++)
        o[(orow + lg * 4 + j) * DIM + h * 64 + nt * 16 + l15] = f2bf_fast(oH1[nt][j] * inv);
    }
  }
}

// ---------------- launch ----------------
extern "C" void kernel_launch(void* const* d_in, const int* in_sizes, int n_in,
                              void* d_out, int out_size, void* d_ws, size_t ws_size,
                              hipStream_t stream) {
  const float* x  = (const float*)d_in[0];
  const float* wq = (const float*)d_in[1];
  const float* wk = (const float*)d_in[2];
  const float* wv = (const float*)d_in[3];
  const float* wo = (const float*)d_in[4];
  float* out = (float*)d_out;

  ushort_t* ws = (ushort_t*)d_ws;
  const long NXB = (long)MROWS * DIM;               // 8388608
  ushort_t* xb   = ws;
  ushort_t* wtq  = xb  + NXB;                       // [2560][2048]
  ushort_t* woT  = wtq + (long)NQKV * DIM;          // [2048][2048]
  ushort_t* qws  = woT + (long)DIM * DIM;           // [4096][2048]
  ushort_t* kws  = qws + NXB;                       // [B,Hkv,T,D]
  ushort_t* vtws = kws + (long)BATCH * NKV * TSEQ * HD;  // [B,Hkv,D,T]
  ushort_t* aws  = vtws + (long)BATCH * NKV * TSEQ * HD; // [4096][2048]
  float2*   tab  = (float2*)(aws + NXB);            // [2048][32] cos/sin

  cast_bf16_k<<<(int)(NXB / 1024), 256, 0, stream>>>(x, xb, (int)(NXB / 4));
  transpose_cast_all<<<dim3(64, 144), 256, 0, stream>>>(wq, wk, wv, wo, wtq, woT);
  rope_tab_k<<<256, 256, 0, stream>>>(tab);

  gemm_bt<0><<<dim3(32, 20), 256, 0, stream>>>(xb, wtq, MROWS, NQKV, DIM,
                                               nullptr, qws, kws, vtws, tab);

  attn_mfma<<<BATCH * NH * (TSEQ / 128), 256, 0, stream>>>(qws, kws, vtws, aws);

  gemm_bt<1><<<dim3(32, 16), 256, 0, stream>>>(aws, woT, MROWS, DIM, DIM,
                                               out, nullptr, nullptr, nullptr, nullptr);
}